// Round 6
// baseline (3368.715 us; speedup 1.0000x reference)
//
#include <hip/hip_runtime.h>
#include <math.h>

// ---------------------------------------------------------------------------
// RNN_63153199120819 — Round 6: fused-phase weight-stationary LSTM.
//   * One barrier per timestep: phase t computes h1(t) AND h0(t+1) (both only
//     need h0(t), broadcast at the previous barrier). 128 barriers vs 255.
//   * Barrier poll = relaxed atomic LOAD (round 5's fetch_add(0) RMW poll
//     serialized 16 pollers on one line and caused 33ms outliers).
//   * h0(t) A-fragments shared in registers between the two gate GEMMs.
//   * MLP GEMM v2: W fragments register-resident (4x fewer W loads/MFMA).
// XCD-locality argument unchanged: 150KB LDS => 1 block/CU, cooperative =>
// 256 co-resident => exactly 32 blocks/XCD; (bi,js) derived from XCC_ID.
// ---------------------------------------------------------------------------

namespace {
constexpr int kT   = 128;
constexpr int kB   = 1024;
constexpr int kLag = 6;
constexpr int kH   = 256;
constexpr int kTc  = 16;          // MLP time chunk
constexpr int kMc  = kTc * kB;    // 16384 rows / chunk
constexpr int kWS  = 520;         // LDS weight row stride (halves)
constexpr int kGS  = 66;          // LDS gate row stride (f32)
constexpr int kLdsBytes = 2 * 64 * kWS * 2 + 64 * kGS * 4;  // 150016 B
}

typedef _Float16 half8 __attribute__((ext_vector_type(8)));
typedef _Float16 half2 __attribute__((ext_vector_type(2)));
typedef float f32x4 __attribute__((ext_vector_type(4)));

__device__ __forceinline__ float sigm(float x) {
    return 1.f / (1.f + exp2f(-1.4426950408889634f * x));
}
__device__ __forceinline__ float tanh_(float x) {
    return 2.f / (1.f + exp2f(-2.8853900817779268f * x)) - 1.f;
}

// coherent (L1-bypass, same-XCD-L2-hit) 16-byte load as two b64 agent atomics
__device__ __forceinline__ half8 ld_h8_coh(const _Float16* p) {
    const unsigned long long* q = (const unsigned long long*)p;
    union { unsigned long long u[2]; half8 h; } r;
    r.u[0] = __hip_atomic_load(q + 0, __ATOMIC_RELAXED, __HIP_MEMORY_SCOPE_AGENT);
    r.u[1] = __hip_atomic_load(q + 1, __ATOMIC_RELAXED, __HIP_MEMORY_SCOPE_AGENT);
    return r.h;
}

// ---------------- prep kernels ---------------------------------------------
__global__ __launch_bounds__(256)
void zero_fill(unsigned int* __restrict__ p)
{
    p[blockIdx.x * 256 + threadIdx.x] = 0u;
}

__global__ __launch_bounds__(256)
void cvt_f2h(const float* __restrict__ s, _Float16* __restrict__ d)
{
    const int i = blockIdx.x * 256 + threadIdx.x;
    d[i] = (_Float16)s[i];
}

__global__ __launch_bounds__(256)
void build_wcat(const float* __restrict__ Wih, const float* __restrict__ Whh,
                _Float16* __restrict__ d)
{
    const int i = blockIdx.x * 256 + threadIdx.x;   // over 1024*512
    const int row = i >> 9, col = i & 511;
    const float v = (col < 256) ? Wih[row * 256 + col] : Whh[row * 256 + col - 256];
    d[i] = (_Float16)v;
}

__global__ __launch_bounds__(256)
void add_bias(const float* __restrict__ a, const float* __restrict__ b,
              float* __restrict__ d)
{
    const int i = blockIdx.x * 256 + threadIdx.x;
    d[i] = a[i] + b[i];
}

// ---------------- first layer: u1 = relu(x @ Wi1^T + bi1), K=6, fp16 out ---
__global__ __launch_bounds__(256)
void in_mlp1(const float* __restrict__ x, const float* __restrict__ Wi1,
             const float* __restrict__ bi1, _Float16* __restrict__ out)
{
    const int idx = blockIdx.x * 256 + threadIdx.x;   // over Mc*H
    const int col = idx & (kH - 1);
    const int row = idx >> 8;
    const float* xr = x + (size_t)row * kLag;
    const float* w  = Wi1 + col * kLag;
    float s = bi1[col];
#pragma unroll
    for (int k = 0; k < kLag; ++k) s = fmaf(xr[k], w[k], s);
    out[idx] = (_Float16)fmaxf(s, 0.f);
}

// ---------------- fp16 MFMA GEMM v2 ----------------------------------------
// C[M,256] = relu(A[M,256]@W^T + b). grid (4, M/128), block 256 (4 waves).
// Wave w: rows [by*128 + w*32, +32) (2 row-tiles), cols [bx*64, +64).
// W fragments register-resident (32 half8): 4x MFMA per W-load vs v1.
__global__ __launch_bounds__(256)
void gemm_h16(const _Float16* __restrict__ A, const _Float16* __restrict__ W,
              const float* __restrict__ bias, _Float16* __restrict__ C)
{
    const int tid = threadIdx.x;
    const int w = tid >> 6, lane = tid & 63, q = lane >> 4, l15 = lane & 15;
    const int n0 = blockIdx.x * 64;
    const int r0 = blockIdx.y * 128 + w * 32;

    half8 bf[4][8];
#pragma unroll
    for (int nt = 0; nt < 4; ++nt)
#pragma unroll
        for (int kk = 0; kk < 8; ++kk)
            bf[nt][kk] = *(const half8*)(W + (size_t)(n0 + nt * 16 + l15) * 256
                                         + kk * 32 + q * 8);
    float bz[4];
#pragma unroll
    for (int nt = 0; nt < 4; ++nt) bz[nt] = bias[n0 + nt * 16 + l15];

#pragma unroll
    for (int rt = 0; rt < 2; ++rt) {
        const _Float16* arow = A + (size_t)(r0 + rt * 16 + l15) * 256 + q * 8;
        half8 af[8];
#pragma unroll
        for (int kk = 0; kk < 8; ++kk) af[kk] = *(const half8*)(arow + kk * 32);
        f32x4 acc[4];
#pragma unroll
        for (int nt = 0; nt < 4; ++nt)
            acc[nt] = (f32x4){bz[nt], bz[nt], bz[nt], bz[nt]};
#pragma unroll
        for (int kk = 0; kk < 8; ++kk)
#pragma unroll
            for (int nt = 0; nt < 4; ++nt)
                acc[nt] = __builtin_amdgcn_mfma_f32_16x16x32_f16(
                    af[kk], bf[nt][kk], acc[nt], 0, 0, 0);
#pragma unroll
        for (int nt = 0; nt < 4; ++nt)
#pragma unroll
            for (int r = 0; r < 4; ++r) {
                const float v = fmaxf(acc[nt][r], 0.f);
                C[(size_t)(r0 + rt * 16 + q * 4 + r) * 256 + n0 + nt * 16 + l15]
                    = (_Float16)v;
            }
    }
}

// ---------------- persistent weight-stationary LSTM ------------------------
// load-poll barrier: one RMW increment, relaxed-load polling (no RMW storm)
__device__ __forceinline__ void xbar(unsigned int* __restrict__ cptr,
                                     unsigned int target, int tid)
{
    __syncthreads();    // drains vmcnt: h stores visible in XCD L2
    if (tid == 0) {
        __hip_atomic_fetch_add(cptr, 1u, __ATOMIC_RELAXED,
                               __HIP_MEMORY_SCOPE_AGENT);
        while (__hip_atomic_load(cptr, __ATOMIC_RELAXED,
                                 __HIP_MEMORY_SCOPE_AGENT) < target)
            __builtin_amdgcn_s_sleep(1);
    }
    __syncthreads();
}

// fragment loaders: af[0..7] <- alo rows, af[8..15] <- ahi rows
template<bool COH>
__device__ __forceinline__ void load_lo(half8* af, const _Float16* p,
                                        int m0, int l15, int q)
{
    const _Float16* r = p + (size_t)(m0 + l15) * 256 + q * 8;
#pragma unroll
    for (int kk = 0; kk < 8; ++kk)
        af[kk] = COH ? ld_h8_coh(r + kk * 32) : *(const half8*)(r + kk * 32);
}
template<bool COH>
__device__ __forceinline__ void load_hi(half8* af, const _Float16* p,
                                        int m0, int l15, int q)
{
    const _Float16* r = p + (size_t)(m0 + l15) * 256 + q * 8;
#pragma unroll
    for (int kk = 0; kk < 8; ++kk)
        af[8 + kk] = COH ? ld_h8_coh(r + kk * 32) : *(const half8*)(r + kk * 32);
}

__device__ __forceinline__ void gate_mfma(const half8* af,
                                          const _Float16* __restrict__ Wl,
                                          int nb, int l15, int q,
                                          f32x4& acc0, f32x4& acc1)
{
    const _Float16* wr0 = Wl + (size_t)(nb + l15) * kWS + q * 8;
    const _Float16* wr1 = Wl + (size_t)(nb + 16 + l15) * kWS + q * 8;
#pragma unroll
    for (int kk = 0; kk < 16; ++kk) {
        acc0 = __builtin_amdgcn_mfma_f32_16x16x32_f16(
            af[kk], *(const half8*)(wr0 + kk * 32), acc0, 0, 0, 0);
        acc1 = __builtin_amdgcn_mfma_f32_16x16x32_f16(
            af[kk], *(const half8*)(wr1 + kk * 32), acc1, 0, 0, 0);
    }
}

// stage gates -> LDS, sync, cell, store h (and optional relu->u)
__device__ __forceinline__ void cell_store(
    float* __restrict__ gl, const f32x4& a0, const f32x4& a1,
    int m0, int nb, int q, int l15, int tid,
    const float* __restrict__ bsc, float* __restrict__ cst,
    _Float16* __restrict__ hout, _Float16* __restrict__ uout)
{
#pragma unroll
    for (int r = 0; r < 4; ++r) {
        gl[(m0 + q * 4 + r) * kGS + nb + l15]      = a0[r];
        gl[(m0 + q * 4 + r) * kGS + nb + 16 + l15] = a1[r];
    }
    __syncthreads();
    const int crow = tid >> 3, cc = (tid & 7) * 2;
    const float* gr = gl + crow * kGS;
    _Float16 hp[2];
#pragma unroll
    for (int e = 0; e < 2; ++e) {
        const float gi = gr[0 * 16 + cc + e] + bsc[e * 4 + 0];
        const float gf = gr[1 * 16 + cc + e] + bsc[e * 4 + 1];
        const float gg = gr[2 * 16 + cc + e] + bsc[e * 4 + 2];
        const float go = gr[3 * 16 + cc + e] + bsc[e * 4 + 3];
        const float c2 = sigm(gf) * cst[e] + sigm(gi) * tanh_(gg);
        cst[e] = c2;
        hp[e] = (_Float16)(sigm(go) * tanh_(c2));
    }
    *(half2*)(hout + (size_t)crow * 256 + cc) = (half2){hp[0], hp[1]};
    if (uout) {
        const _Float16 z = (_Float16)0.f;
        *(half2*)(uout + (size_t)crow * 256 + cc) =
            (half2){hp[0] > z ? hp[0] : z, hp[1] > z ? hp[1] : z};
    }
}

__global__ __launch_bounds__(512, 1)
void lstm_all(_Float16* __restrict__ ubuf,
              const _Float16* __restrict__ Wc0, const _Float16* __restrict__ Wc1,
              const float* __restrict__ bc0, const float* __restrict__ bc1,
              _Float16* __restrict__ h0b, _Float16* __restrict__ h1b,
              unsigned int* __restrict__ cnt)
{
    extern __shared__ char lds[];
    _Float16* Wl = (_Float16*)lds;                         // [2][64][kWS]
    float* gl = (float*)(lds + 2 * 64 * kWS * 2);          // [64][kGS]

    const int tid = threadIdx.x;
    const int w = tid >> 6, lane = tid & 63, q = lane >> 4, l15 = lane & 15;
    const int m0 = (w & 3) * 16;        // row tile within 64
    const int nb = (w >> 2) * 32;       // gate-col tile base (0 or 32)

    // ---- XCD discovery -> (bi, js): barrier groups provably intra-XCD ----
    __shared__ int sh_bi, sh_js;
    if (tid == 0) {
        unsigned int xcd = __builtin_amdgcn_s_getreg(20 | (31 << 11)) & 7u;
        unsigned int rank = __hip_atomic_fetch_add(cnt + 512 + xcd * 16, 1u,
            __ATOMIC_RELAXED, __HIP_MEMORY_SCOPE_AGENT);
        sh_bi = (int)(xcd * 2 + (rank >> 4));
        sh_js = (int)(rank & 15);
    }
    __syncthreads();
    const int bi = sh_bi, js = sh_js;
    unsigned int* cptr = cnt + bi * 32;   // group counter, 128B spaced

    // ---- load weight slices to LDS (once) ----
    for (int i = tid; i < 2 * 64 * 64; i += 512) {         // half8 units
        const int l = i >> 12;
        const int r = (i >> 6) & 63;
        const int ks = i & 63;
        const int g = r >> 4, c = r & 15;
        const _Float16* src = (l ? Wc1 : Wc0)
            + (size_t)(g * 256 + js * 16 + c) * 512 + ks * 8;
        *(half8*)&Wl[(size_t)l * 64 * kWS + (size_t)r * kWS + ks * 8] =
            *(const half8*)src;
    }

    // ---- per-thread biases (cell mapping: row tid>>3, cols cc, cc+1) ----
    const int cc = (tid & 7) * 2;
    float bs0[8], bs1[8];
#pragma unroll
    for (int e = 0; e < 2; ++e)
#pragma unroll
        for (int g = 0; g < 4; ++g) {
            bs0[e * 4 + g] = bc0[g * 256 + js * 16 + cc + e];
            bs1[e * 4 + g] = bc1[g * 256 + js * 16 + cc + e];
        }
    float cst0[2] = {0.f, 0.f}, cst1[2] = {0.f, 0.f};
    const size_t rbase = (size_t)bi * 64 * 256;     // row offset of this bi
    const size_t obase = rbase + js * 16;           // + col slice (outputs)
    __syncthreads();

    // ---- prologue: h0(0) from [u(0) | 0]  (h0b parity-1 is zeroed) ----
    {
        half8 afP[16];
        load_lo<false>(afP, ubuf + rbase, m0, l15, q);
        load_hi<true >(afP, h0b + (size_t)kB * 256 + rbase, m0, l15, q);
        f32x4 a0 = {0.f, 0.f, 0.f, 0.f}, a1 = {0.f, 0.f, 0.f, 0.f};
        gate_mfma(afP, Wl, nb, l15, q, a0, a1);
        cell_store(gl, a0, a1, m0, nb, q, l15, tid, bs0, cst0,
                   h0b + obase, nullptr);
        xbar(cptr, 16u, tid);
    }

    // ---- fused phases: t computes h1(t) and h0(t+1), one barrier ----
    for (int t = 0; t < kT; ++t) {
        const size_t p  = (size_t)(t & 1) * kB * 256;        // h0(t)/h1(t)
        const size_t pn = (size_t)((t & 1) ^ 1) * kB * 256;  // h0(t+1)/h1(t-1)
        half8 afA[16], afB[16];
        // layer-1 A: [h0(t) | h1(t-1)]
        load_lo<true>(afA, h0b + p + rbase, m0, l15, q);
        load_hi<true>(afA, h1b + pn + rbase, m0, l15, q);
        const bool hasB = (t < kT - 1);
        if (hasB) {
            // layer-0(t+1) A: [u(t+1) | h0(t)] — hi half shared with afA lo
            load_lo<false>(afB, ubuf + (size_t)(t + 1) * kB * 256 + rbase,
                           m0, l15, q);
#pragma unroll
            for (int kk = 0; kk < 8; ++kk) afB[8 + kk] = afA[kk];
        }
        f32x4 aA0 = {0.f,0.f,0.f,0.f}, aA1 = {0.f,0.f,0.f,0.f};
        f32x4 aB0 = {0.f,0.f,0.f,0.f}, aB1 = {0.f,0.f,0.f,0.f};
        gate_mfma(afA, Wl + 64 * kWS, nb, l15, q, aA0, aA1);
        if (hasB) gate_mfma(afB, Wl, nb, l15, q, aB0, aB1);

        // h1(t) -> h1b[p], relu -> ubuf[t]
        cell_store(gl, aA0, aA1, m0, nb, q, l15, tid, bs1, cst1,
                   h1b + p + obase,
                   ubuf + (size_t)t * kB * 256 + obase);
        if (hasB) {
            __syncthreads();   // cellA's gl reads done before stage-B writes
            cell_store(gl, aB0, aB1, m0, nb, q, l15, tid, bs0, cst0,
                       h0b + pn + obase, nullptr);
            xbar(cptr, (unsigned)(16 * (t + 2)), tid);
        }
    }
}

// ---------------- last layer: y = y2 @ Wo3^T + bo3, N=6, fp16 in -----------
__global__ __launch_bounds__(256)
void out_mlp3(const _Float16* __restrict__ y2, const float* __restrict__ Wo3,
              const float* __restrict__ bo3, float* __restrict__ out)
{
    const int lane = threadIdx.x & 63;
    const int row  = blockIdx.x * 4 + (threadIdx.x >> 6);
    const _Float16* yr = y2 + (size_t)row * kH + lane * 4;
    const float a0 = (float)yr[0], a1 = (float)yr[1], a2 = (float)yr[2], a3 = (float)yr[3];
    float s[kLag];
#pragma unroll
    for (int o = 0; o < kLag; ++o) {
        const float4 wv = *(const float4*)(Wo3 + o * kH + lane * 4);
        s[o] = a0 * wv.x + a1 * wv.y + a2 * wv.z + a3 * wv.w;
    }
#pragma unroll
    for (int off = 32; off > 0; off >>= 1) {
#pragma unroll
        for (int o = 0; o < kLag; ++o) s[o] += __shfl_down(s[o], off);
    }
    if (lane == 0) {
#pragma unroll
        for (int o = 0; o < kLag; ++o)
            out[(size_t)row * kLag + o] = s[o] + bo3[o];
    }
}

// ---------------------------------------------------------------------------
extern "C" void kernel_launch(void* const* d_in, const int* in_sizes, int n_in,
                              void* d_out, int out_size, void* d_ws, size_t ws_size,
                              hipStream_t stream)
{
    const float* x    = (const float*)d_in[0];
    const float* Wi1  = (const float*)d_in[1];
    const float* bi1  = (const float*)d_in[2];
    const float* Wi2  = (const float*)d_in[3];
    const float* bi2  = (const float*)d_in[4];
    const float* Wi3  = (const float*)d_in[5];
    const float* bi3  = (const float*)d_in[6];
    const float* Wih0 = (const float*)d_in[7];
    const float* Whh0 = (const float*)d_in[8];
    const float* bih0 = (const float*)d_in[9];
    const float* bhh0 = (const float*)d_in[10];
    const float* Wih1 = (const float*)d_in[11];
    const float* Whh1 = (const float*)d_in[12];
    const float* bih1 = (const float*)d_in[13];
    const float* bhh1 = (const float*)d_in[14];
    const float* Wo1  = (const float*)d_in[15];
    const float* bo1  = (const float*)d_in[16];
    const float* Wo2  = (const float*)d_in[17];
    const float* bo2  = (const float*)d_in[18];
    const float* Wo3  = (const float*)d_in[19];
    const float* bo3  = (const float*)d_in[20];
    float* outp = (float*)d_out;

    // ---- workspace layout ----
    char* p = (char*)d_ws;
    _Float16* ubuf = (_Float16*)p;  p += (size_t)kT * kB * kH * 2;   // 67.1 MB
    _Float16* s1   = (_Float16*)p;  p += (size_t)kMc * kH * 2;       // 8 MB
    _Float16* s2   = (_Float16*)p;  p += (size_t)kMc * kH * 2;       // 8 MB
    _Float16* Wc0  = (_Float16*)p;  p += (size_t)1024 * 512 * 2;     // 1 MB
    _Float16* Wc1  = (_Float16*)p;  p += (size_t)1024 * 512 * 2;     // 1 MB
    _Float16* W2h  = (_Float16*)p;  p += (size_t)kH * kH * 2;
    _Float16* W3h  = (_Float16*)p;  p += (size_t)kH * kH * 2;
    _Float16* Wo1h = (_Float16*)p;  p += (size_t)kH * kH * 2;
    _Float16* Wo2h = (_Float16*)p;  p += (size_t)kH * kH * 2;
    float* bc0 = (float*)p;  p += 1024 * 4;
    float* bc1 = (float*)p;  p += 1024 * 4;
    // zeroed region: h double-buffers + counters (contiguous)
    _Float16* h0b = (_Float16*)p;  p += (size_t)2 * kB * kH * 2;     // 1 MB
    _Float16* h1b = (_Float16*)p;  p += (size_t)2 * kB * kH * 2;     // 1 MB
    unsigned int* cnt = (unsigned int*)p;  p += 4096;  // 16 group + 8 xcd ctrs

    // ---- prep ----
    zero_fill<<<2052, 256, 0, stream>>>((unsigned int*)h0b);
    cvt_f2h<<<kH * kH / 256, 256, 0, stream>>>(Wi2, W2h);
    cvt_f2h<<<kH * kH / 256, 256, 0, stream>>>(Wi3, W3h);
    cvt_f2h<<<kH * kH / 256, 256, 0, stream>>>(Wo1, Wo1h);
    cvt_f2h<<<kH * kH / 256, 256, 0, stream>>>(Wo2, Wo2h);
    build_wcat<<<1024 * 512 / 256, 256, 0, stream>>>(Wih0, Whh0, Wc0);
    build_wcat<<<1024 * 512 / 256, 256, 0, stream>>>(Wih1, Whh1, Wc1);
    add_bias<<<4, 256, 0, stream>>>(bih0, bhh0, bc0);
    add_bias<<<4, 256, 0, stream>>>(bih1, bhh1, bc1);

    // ---- input MLP (chunked): x -> s1 -> s2 -> ubuf ----
    for (int c = 0; c < kT / kTc; ++c) {
        in_mlp1<<<kMc * kH / 256, 256, 0, stream>>>(
            x + (size_t)c * kMc * kLag, Wi1, bi1, s1);
        gemm_h16<<<dim3(4, kMc / 128), 256, 0, stream>>>(s1, W2h, bi2, s2);
        gemm_h16<<<dim3(4, kMc / 128), 256, 0, stream>>>(
            s2, W3h, bi3, ubuf + (size_t)c * kMc * kH);
    }

    // ---- LSTM: cooperative weight-stationary persistent kernel ----
    static bool attr_set = false;
    if (!attr_set) {
        hipFuncSetAttribute((const void*)lstm_all,
                            hipFuncAttributeMaxDynamicSharedMemorySize, kLdsBytes);
        attr_set = true;
    }
    void* args[] = {&ubuf, &Wc0, &Wc1, &bc0, &bc1, &h0b, &h1b, &cnt};
    hipLaunchCooperativeKernel((const void*)lstm_all, dim3(256), dim3(512),
                               args, kLdsBytes, stream);

    // ---- output MLP (chunked): ubuf -> s1 -> s2 -> out ----
    for (int c = 0; c < kT / kTc; ++c) {
        gemm_h16<<<dim3(4, kMc / 128), 256, 0, stream>>>(
            ubuf + (size_t)c * kMc * kH, Wo1h, bo1, s1);
        gemm_h16<<<dim3(4, kMc / 128), 256, 0, stream>>>(s1, Wo2h, bo2, s2);
        out_mlp3<<<kMc / 4, 256, 0, stream>>>(
            s2, Wo3, bo3, outp + (size_t)c * kMc * kLag);
    }
}

// Round 7
// 2594.209 us; speedup vs baseline: 1.2986x; 1.2986x over previous
//
#include <hip/hip_runtime.h>
#include <math.h>

// ---------------------------------------------------------------------------
// RNN_63153199120819 — Round 7: register-resident weights + wave-specialized
// fused phases.
//   * Round-6 postmortem: phase work (not barrier) dominates — 128 ds_read_b128
//     per wave-phase for B-fragments + serialized coherent loads. Fix: each
//     wave keeps its B-fragments (32 x half8 = 128 VGPR) in REGISTERS; waves
//     0-3 compute layer 1, waves 4-7 layer 0 (both need only h0(t) after the
//     barrier). A-operands gathered into raw u64 arrays (all loads issued
//     before first use -> pipelined, single waitcnt).
//   * LDS = gate staging only (34 KB used, 96 KB reserved to force 1 block/CU
//     so the XCD-rank -> (bi,js) mapping stays exact: 32 blocks/XCD).
//   * MLP: kTc 16->32 (half the launches), gemm v2 unchanged.
// ---------------------------------------------------------------------------

namespace {
constexpr int kT   = 128;
constexpr int kB   = 1024;
constexpr int kLag = 6;
constexpr int kH   = 256;
constexpr int kTc  = 32;          // MLP time chunk
constexpr int kMc  = kTc * kB;    // 32768 rows / chunk
constexpr int kGS  = 66;          // LDS gate row stride (f32)
constexpr int kLdsForce = 98304;  // >80KB => at most 1 block/CU
}

typedef _Float16 half8 __attribute__((ext_vector_type(8)));
typedef _Float16 half2 __attribute__((ext_vector_type(2)));
typedef float f32x4 __attribute__((ext_vector_type(4)));
typedef unsigned long long u64;

__device__ __forceinline__ float sigm(float x) {
    return 1.f / (1.f + exp2f(-1.4426950408889634f * x));
}
__device__ __forceinline__ float tanh_(float x) {
    return 2.f / (1.f + exp2f(-2.8853900817779268f * x)) - 1.f;
}

__device__ __forceinline__ half8 pack(u64 a, u64 b) {
    union { u64 u[2]; half8 h; } r;
    r.u[0] = a; r.u[1] = b;
    return r.h;
}

// ---------------- prep kernels ---------------------------------------------
__global__ __launch_bounds__(256)
void zero_fill(unsigned int* __restrict__ p)
{
    p[blockIdx.x * 256 + threadIdx.x] = 0u;
}

__global__ __launch_bounds__(256)
void cvt_f2h(const float* __restrict__ s, _Float16* __restrict__ d)
{
    const int i = blockIdx.x * 256 + threadIdx.x;
    d[i] = (_Float16)s[i];
}

__global__ __launch_bounds__(256)
void build_wcat(const float* __restrict__ Wih, const float* __restrict__ Whh,
                _Float16* __restrict__ d)
{
    const int i = blockIdx.x * 256 + threadIdx.x;   // over 1024*512
    const int row = i >> 9, col = i & 511;
    const float v = (col < 256) ? Wih[row * 256 + col] : Whh[row * 256 + col - 256];
    d[i] = (_Float16)v;
}

__global__ __launch_bounds__(256)
void add_bias(const float* __restrict__ a, const float* __restrict__ b,
              float* __restrict__ d)
{
    const int i = blockIdx.x * 256 + threadIdx.x;
    d[i] = a[i] + b[i];
}

// ---------------- first layer: u1 = relu(x @ Wi1^T + bi1), K=6, fp16 out ---
__global__ __launch_bounds__(256)
void in_mlp1(const float* __restrict__ x, const float* __restrict__ Wi1,
             const float* __restrict__ bi1, _Float16* __restrict__ out)
{
    const int idx = blockIdx.x * 256 + threadIdx.x;   // over Mc*H
    const int col = idx & (kH - 1);
    const int row = idx >> 8;
    const float* xr = x + (size_t)row * kLag;
    const float* w  = Wi1 + col * kLag;
    float s = bi1[col];
#pragma unroll
    for (int k = 0; k < kLag; ++k) s = fmaf(xr[k], w[k], s);
    out[idx] = (_Float16)fmaxf(s, 0.f);
}

// ---------------- fp16 MFMA GEMM v2 (unchanged, validated) -----------------
__global__ __launch_bounds__(256)
void gemm_h16(const _Float16* __restrict__ A, const _Float16* __restrict__ W,
              const float* __restrict__ bias, _Float16* __restrict__ C)
{
    const int tid = threadIdx.x;
    const int w = tid >> 6, lane = tid & 63, q = lane >> 4, l15 = lane & 15;
    const int n0 = blockIdx.x * 64;
    const int r0 = blockIdx.y * 128 + w * 32;

    half8 bf[4][8];
#pragma unroll
    for (int nt = 0; nt < 4; ++nt)
#pragma unroll
        for (int kk = 0; kk < 8; ++kk)
            bf[nt][kk] = *(const half8*)(W + (size_t)(n0 + nt * 16 + l15) * 256
                                         + kk * 32 + q * 8);
    float bz[4];
#pragma unroll
    for (int nt = 0; nt < 4; ++nt) bz[nt] = bias[n0 + nt * 16 + l15];

#pragma unroll
    for (int rt = 0; rt < 2; ++rt) {
        const _Float16* arow = A + (size_t)(r0 + rt * 16 + l15) * 256 + q * 8;
        half8 af[8];
#pragma unroll
        for (int kk = 0; kk < 8; ++kk) af[kk] = *(const half8*)(arow + kk * 32);
        f32x4 acc[4];
#pragma unroll
        for (int nt = 0; nt < 4; ++nt)
            acc[nt] = (f32x4){bz[nt], bz[nt], bz[nt], bz[nt]};
#pragma unroll
        for (int kk = 0; kk < 8; ++kk)
#pragma unroll
            for (int nt = 0; nt < 4; ++nt)
                acc[nt] = __builtin_amdgcn_mfma_f32_16x16x32_f16(
                    af[kk], bf[nt][kk], acc[nt], 0, 0, 0);
#pragma unroll
        for (int nt = 0; nt < 4; ++nt)
#pragma unroll
            for (int r = 0; r < 4; ++r) {
                const float v = fmaxf(acc[nt][r], 0.f);
                C[(size_t)(r0 + rt * 16 + q * 4 + r) * 256 + n0 + nt * 16 + l15]
                    = (_Float16)v;
            }
    }
}

// ---------------- persistent LSTM helpers ----------------------------------
__device__ __forceinline__ void xbar(unsigned int* __restrict__ cptr,
                                     unsigned int target, int tid)
{
    __syncthreads();    // drains vmcnt: h stores visible in XCD L2
    if (tid == 0) {
        __hip_atomic_fetch_add(cptr, 1u, __ATOMIC_RELAXED,
                               __HIP_MEMORY_SCOPE_AGENT);
        while (__hip_atomic_load(cptr, __ATOMIC_RELAXED,
                                 __HIP_MEMORY_SCOPE_AGENT) < target)
            __builtin_amdgcn_s_sleep(1);
    }
    __syncthreads();
}

// gather A-row: ua[0..15] <- lo (K 0..255), ua[16..31] <- hi (K 256..511).
// All loads issued before any use => pipelined (single waitcnt at consume).
template<bool C0, bool C1>
__device__ __forceinline__ void gather(const _Float16* lo, const _Float16* hi,
                                       int row, int q, u64* ua)
{
    const u64* plo = (const u64*)(lo + (size_t)row * 256 + q * 8);
    const u64* phi = (const u64*)(hi + (size_t)row * 256 + q * 8);
#pragma unroll
    for (int kk = 0; kk < 8; ++kk) {
        if (C0) {
            ua[2*kk]   = __hip_atomic_load(plo + kk*8,     __ATOMIC_RELAXED,
                                           __HIP_MEMORY_SCOPE_AGENT);
            ua[2*kk+1] = __hip_atomic_load(plo + kk*8 + 1, __ATOMIC_RELAXED,
                                           __HIP_MEMORY_SCOPE_AGENT);
        } else {
            ua[2*kk]   = plo[kk*8];
            ua[2*kk+1] = plo[kk*8 + 1];
        }
        if (C1) {
            ua[16+2*kk] = __hip_atomic_load(phi + kk*8,     __ATOMIC_RELAXED,
                                            __HIP_MEMORY_SCOPE_AGENT);
            ua[17+2*kk] = __hip_atomic_load(phi + kk*8 + 1, __ATOMIC_RELAXED,
                                            __HIP_MEMORY_SCOPE_AGENT);
        } else {
            ua[16+2*kk] = phi[kk*8];
            ua[17+2*kk] = phi[kk*8 + 1];
        }
    }
}
// lo-only gather (prologue)
__device__ __forceinline__ void gather_lo(const _Float16* lo, int row, int q,
                                          u64* ua)
{
    const u64* plo = (const u64*)(lo + (size_t)row * 256 + q * 8);
#pragma unroll
    for (int kk = 0; kk < 8; ++kk) {
        ua[2*kk]   = plo[kk*8];
        ua[2*kk+1] = plo[kk*8 + 1];
    }
}

template<int KK>
__device__ __forceinline__ void mfma_rt(const u64* ua, const half8* B0,
                                        const half8* B1, f32x4& a0, f32x4& a1)
{
#pragma unroll
    for (int kk = 0; kk < KK; ++kk) {
        const half8 af = pack(ua[2*kk], ua[2*kk+1]);
        a0 = __builtin_amdgcn_mfma_f32_16x16x32_f16(af, B0[kk], a0, 0, 0, 0);
        a1 = __builtin_amdgcn_mfma_f32_16x16x32_f16(af, B1[kk], a1, 0, 0, 0);
    }
}

__device__ __forceinline__ void gstore(float* __restrict__ gl, int m0, int nb,
                                       int q, int l15,
                                       const f32x4& a0, const f32x4& a1)
{
#pragma unroll
    for (int r = 0; r < 4; ++r) {
        gl[(m0 + q*4 + r) * kGS + nb + l15]      = a0[r];
        gl[(m0 + q*4 + r) * kGS + nb + 16 + l15] = a1[r];
    }
}

__device__ __forceinline__ void cell_one(const float* __restrict__ gl,
    int crow, int cc, const float* __restrict__ bs, float* __restrict__ cst,
    _Float16* __restrict__ hout, _Float16* __restrict__ uout)
{
    const float* gr = gl + crow * kGS;
    _Float16 hp[2];
#pragma unroll
    for (int e = 0; e < 2; ++e) {
        const float gi = gr[0*16 + cc + e] + bs[e*4 + 0];
        const float gf = gr[1*16 + cc + e] + bs[e*4 + 1];
        const float gg = gr[2*16 + cc + e] + bs[e*4 + 2];
        const float go = gr[3*16 + cc + e] + bs[e*4 + 3];
        const float c2 = sigm(gf) * cst[e] + sigm(gi) * tanh_(gg);
        cst[e] = c2;
        hp[e] = (_Float16)(sigm(go) * tanh_(c2));
    }
    *(half2*)(hout + (size_t)crow * 256 + cc) = (half2){hp[0], hp[1]};
    if (uout) {
        const _Float16 z = (_Float16)0.f;
        *(half2*)(uout + (size_t)crow * 256 + cc) =
            (half2){hp[0] > z ? hp[0] : z, hp[1] > z ? hp[1] : z};
    }
}

// ---------------- persistent LSTM kernel -----------------------------------
__global__ __launch_bounds__(512, 2)
void lstm_all(_Float16* __restrict__ ubuf,
              const _Float16* __restrict__ Wc0, const _Float16* __restrict__ Wc1,
              const float* __restrict__ bc0, const float* __restrict__ bc1,
              _Float16* __restrict__ h0b, _Float16* __restrict__ h1b,
              unsigned int* __restrict__ cnt)
{
    extern __shared__ char lds[];
    float* gl0 = (float*)lds;             // [64][kGS] layer-0 gates
    float* gl1 = gl0 + 64 * kGS;          // [64][kGS] layer-1 gates

    const int tid = threadIdx.x;
    const int w = tid >> 6, lane = tid & 63, q = lane >> 4, l15 = lane & 15;
    const int wl = w & 3;
    const int rtb = (wl >> 1) * 2;        // row-tile base (0 or 2)
    const int nb  = (wl & 1) * 32;        // gate-col base (0 or 32)
    const int lyr = (w < 4) ? 1 : 0;      // wave's layer

    // ---- XCD discovery -> (bi, js): 96KB LDS => 1 block/CU => 32/XCD ----
    __shared__ int sh_bi, sh_js;
    if (tid == 0) {
        unsigned int xcd = __builtin_amdgcn_s_getreg(20 | (31 << 11)) & 7u;
        unsigned int rank = __hip_atomic_fetch_add(cnt + 512 + xcd * 16, 1u,
            __ATOMIC_RELAXED, __HIP_MEMORY_SCOPE_AGENT);
        sh_bi = (int)(xcd * 2 + (rank >> 4));
        sh_js = (int)(rank & 15);
    }
    __syncthreads();
    const int bi = sh_bi, js = sh_js;
    unsigned int* cptr = cnt + bi * 32;

    // ---- B-fragments of this wave's layer/cols -> 32 half8 in registers ----
    const _Float16* WcL = lyr ? Wc1 : Wc0;
    half8 Bf[2][16];
#pragma unroll
    for (int ct = 0; ct < 2; ++ct) {
        const _Float16* wr = WcL
            + (size_t)(((nb >> 4) + ct) * 256 + js * 16 + l15) * 512 + q * 8;
#pragma unroll
        for (int kk = 0; kk < 16; ++kk)
            Bf[ct][kk] = *(const half8*)(wr + kk * 32);
    }

    // ---- per-thread biases / states (cell: row tid>>3, cols cc, cc+1) ----
    const int cc = (tid & 7) * 2;
    const int crow = tid >> 3;
    float bs0[8], bs1[8];
#pragma unroll
    for (int e = 0; e < 2; ++e)
#pragma unroll
        for (int g = 0; g < 4; ++g) {
            bs0[e*4 + g] = bc0[g * 256 + js * 16 + cc + e];
            bs1[e*4 + g] = bc1[g * 256 + js * 16 + cc + e];
        }
    float cst0[2] = {0.f, 0.f}, cst1[2] = {0.f, 0.f};
    const size_t rbase = (size_t)bi * 64 * 256;
    const size_t obase = rbase + js * 16;

    // ---- prologue: h0(0) = cell([u(0) | 0] @ W0^T)  -> h0b parity 0 ----
    if (lyr == 0) {
#pragma unroll
        for (int rt = 0; rt < 2; ++rt) {
            u64 ua[16];
            gather_lo(ubuf + rbase, (rtb + rt) * 16 + l15, q, ua);
            f32x4 a0 = {0.f,0.f,0.f,0.f}, a1 = {0.f,0.f,0.f,0.f};
            mfma_rt<8>(ua, Bf[0], Bf[1], a0, a1);
            gstore(gl0, (rtb + rt) * 16, nb, q, l15, a0, a1);
        }
    }
    __syncthreads();
    cell_one(gl0, crow, cc, bs0, cst0, h0b + obase, nullptr);
    xbar(cptr, 16u, tid);

    // ---- fused phases: t computes h1(t) (waves 0-3) + h0(t+1) (waves 4-7) --
    for (int t = 0; t < kT; ++t) {
        const size_t p  = (size_t)(t & 1) * kB * 256;
        const size_t pn = (size_t)((t & 1) ^ 1) * kB * 256;
        const bool hasB = (t < kT - 1);
        if (lyr == 1) {
            // layer-1 A = [h0(t) | h1(t-1)]
#pragma unroll
            for (int rt = 0; rt < 2; ++rt) {
                u64 ua[32];
                gather<true, true>(h0b + p + rbase, h1b + pn + rbase,
                                   (rtb + rt) * 16 + l15, q, ua);
                f32x4 a0 = {0.f,0.f,0.f,0.f}, a1 = {0.f,0.f,0.f,0.f};
                mfma_rt<16>(ua, Bf[0], Bf[1], a0, a1);
                gstore(gl1, (rtb + rt) * 16, nb, q, l15, a0, a1);
            }
        } else if (hasB) {
            // layer-0 A = [u(t+1) | h0(t)]
#pragma unroll
            for (int rt = 0; rt < 2; ++rt) {
                u64 ua[32];
                gather<false, true>(ubuf + (size_t)(t + 1) * kB * 256 + rbase,
                                    h0b + p + rbase,
                                    (rtb + rt) * 16 + l15, q, ua);
                f32x4 a0 = {0.f,0.f,0.f,0.f}, a1 = {0.f,0.f,0.f,0.f};
                mfma_rt<16>(ua, Bf[0], Bf[1], a0, a1);
                gstore(gl0, (rtb + rt) * 16, nb, q, l15, a0, a1);
            }
        }
        __syncthreads();
        cell_one(gl1, crow, cc, bs1, cst1, h1b + p + obase,
                 ubuf + (size_t)t * kB * 256 + obase);
        if (hasB) {
            cell_one(gl0, crow, cc, bs0, cst0, h0b + pn + obase, nullptr);
            xbar(cptr, (unsigned)(16 * (t + 2)), tid);
        }
    }
}

// ---------------- last layer: y = y2 @ Wo3^T + bo3, N=6, fp16 in -----------
__global__ __launch_bounds__(256)
void out_mlp3(const _Float16* __restrict__ y2, const float* __restrict__ Wo3,
              const float* __restrict__ bo3, float* __restrict__ out)
{
    const int lane = threadIdx.x & 63;
    const int row  = blockIdx.x * 4 + (threadIdx.x >> 6);
    const _Float16* yr = y2 + (size_t)row * kH + lane * 4;
    const float a0 = (float)yr[0], a1 = (float)yr[1], a2 = (float)yr[2], a3 = (float)yr[3];
    float s[kLag];
#pragma unroll
    for (int o = 0; o < kLag; ++o) {
        const float4 wv = *(const float4*)(Wo3 + o * kH + lane * 4);
        s[o] = a0 * wv.x + a1 * wv.y + a2 * wv.z + a3 * wv.w;
    }
#pragma unroll
    for (int off = 32; off > 0; off >>= 1) {
#pragma unroll
        for (int o = 0; o < kLag; ++o) s[o] += __shfl_down(s[o], off);
    }
    if (lane == 0) {
#pragma unroll
        for (int o = 0; o < kLag; ++o)
            out[(size_t)row * kLag + o] = s[o] + bo3[o];
    }
}

// ---------------------------------------------------------------------------
extern "C" void kernel_launch(void* const* d_in, const int* in_sizes, int n_in,
                              void* d_out, int out_size, void* d_ws, size_t ws_size,
                              hipStream_t stream)
{
    const float* x    = (const float*)d_in[0];
    const float* Wi1  = (const float*)d_in[1];
    const float* bi1  = (const float*)d_in[2];
    const float* Wi2  = (const float*)d_in[3];
    const float* bi2  = (const float*)d_in[4];
    const float* Wi3  = (const float*)d_in[5];
    const float* bi3  = (const float*)d_in[6];
    const float* Wih0 = (const float*)d_in[7];
    const float* Whh0 = (const float*)d_in[8];
    const float* bih0 = (const float*)d_in[9];
    const float* bhh0 = (const float*)d_in[10];
    const float* Wih1 = (const float*)d_in[11];
    const float* Whh1 = (const float*)d_in[12];
    const float* bih1 = (const float*)d_in[13];
    const float* bhh1 = (const float*)d_in[14];
    const float* Wo1  = (const float*)d_in[15];
    const float* bo1  = (const float*)d_in[16];
    const float* Wo2  = (const float*)d_in[17];
    const float* bo2  = (const float*)d_in[18];
    const float* Wo3  = (const float*)d_in[19];
    const float* bo3  = (const float*)d_in[20];
    float* outp = (float*)d_out;

    // ---- workspace layout (~106 MB) ----
    char* p = (char*)d_ws;
    _Float16* ubuf = (_Float16*)p;  p += (size_t)kT * kB * kH * 2;   // 67.1 MB
    _Float16* s1   = (_Float16*)p;  p += (size_t)kMc * kH * 2;       // 16.8 MB
    _Float16* s2   = (_Float16*)p;  p += (size_t)kMc * kH * 2;       // 16.8 MB
    _Float16* Wc0  = (_Float16*)p;  p += (size_t)1024 * 512 * 2;     // 1 MB
    _Float16* Wc1  = (_Float16*)p;  p += (size_t)1024 * 512 * 2;     // 1 MB
    _Float16* W2h  = (_Float16*)p;  p += (size_t)kH * kH * 2;
    _Float16* W3h  = (_Float16*)p;  p += (size_t)kH * kH * 2;
    _Float16* Wo1h = (_Float16*)p;  p += (size_t)kH * kH * 2;
    _Float16* Wo2h = (_Float16*)p;  p += (size_t)kH * kH * 2;
    float* bc0 = (float*)p;  p += 1024 * 4;
    float* bc1 = (float*)p;  p += 1024 * 4;
    // zeroed region: h double-buffers + counters (contiguous)
    _Float16* h0b = (_Float16*)p;  p += (size_t)2 * kB * kH * 2;     // 1 MB
    _Float16* h1b = (_Float16*)p;  p += (size_t)2 * kB * kH * 2;     // 1 MB
    unsigned int* cnt = (unsigned int*)p;  p += 4096;  // 16 group + 8 xcd ctrs

    // ---- prep ----
    zero_fill<<<2052, 256, 0, stream>>>((unsigned int*)h0b);
    cvt_f2h<<<kH * kH / 256, 256, 0, stream>>>(Wi2, W2h);
    cvt_f2h<<<kH * kH / 256, 256, 0, stream>>>(Wi3, W3h);
    cvt_f2h<<<kH * kH / 256, 256, 0, stream>>>(Wo1, Wo1h);
    cvt_f2h<<<kH * kH / 256, 256, 0, stream>>>(Wo2, Wo2h);
    build_wcat<<<1024 * 512 / 256, 256, 0, stream>>>(Wih0, Whh0, Wc0);
    build_wcat<<<1024 * 512 / 256, 256, 0, stream>>>(Wih1, Whh1, Wc1);
    add_bias<<<4, 256, 0, stream>>>(bih0, bhh0, bc0);
    add_bias<<<4, 256, 0, stream>>>(bih1, bhh1, bc1);

    // ---- input MLP (chunked): x -> s1 -> s2 -> ubuf ----
    for (int c = 0; c < kT / kTc; ++c) {
        in_mlp1<<<kMc * kH / 256, 256, 0, stream>>>(
            x + (size_t)c * kMc * kLag, Wi1, bi1, s1);
        gemm_h16<<<dim3(4, kMc / 128), 256, 0, stream>>>(s1, W2h, bi2, s2);
        gemm_h16<<<dim3(4, kMc / 128), 256, 0, stream>>>(
            s2, W3h, bi3, ubuf + (size_t)c * kMc * kH);
    }

    // ---- LSTM: cooperative, weights in VGPRs, XCD-local barriers ----
    static bool attr_set = false;
    if (!attr_set) {
        hipFuncSetAttribute((const void*)lstm_all,
                            hipFuncAttributeMaxDynamicSharedMemorySize, kLdsForce);
        attr_set = true;
    }
    void* args[] = {&ubuf, &Wc0, &Wc1, &bc0, &bc1, &h0b, &h1b, &cnt};
    hipLaunchCooperativeKernel((const void*)lstm_all, dim3(256), dim3(512),
                               args, kLdsForce, stream);

    // ---- output MLP (chunked): ubuf -> s1 -> s2 -> out ----
    for (int c = 0; c < kT / kTc; ++c) {
        gemm_h16<<<dim3(4, kMc / 128), 256, 0, stream>>>(
            ubuf + (size_t)c * kMc * kH, Wo1h, bo1, s1);
        gemm_h16<<<dim3(4, kMc / 128), 256, 0, stream>>>(s1, Wo2h, bo2, s2);
        out_mlp3<<<kMc / 4, 256, 0, stream>>>(
            s2, Wo3, bo3, outp + (size_t)c * kMc * kLag);
    }
}

// Round 8
// 2065.716 us; speedup vs baseline: 1.6308x; 1.2558x over previous
//
#include <hip/hip_runtime.h>
#include <math.h>

// ---------------------------------------------------------------------------
// RNN_63153199120819 — Round 8: pipelined coherent loads via inline asm.
// R7 postmortem: phase time tracks the COUNT of agent-scope atomic loads
// (~500 cy each, serialized) — not MFMA/LDS/barrier. This round replaces all
// per-lane atomic h-loads with plain `global_load_dwordx4 ... sc0 sc1` inline
// asm (same coherence behavior: bypass L1+L2, serviced at coherence point;
// but fully pipelined, one s_waitcnt per 16-load batch, dependency-tied via
// "+v" constraints). h-stores become sc0 sc1 write-through; xbar drains vmcnt
// explicitly per-wave (asm stores are invisible to the compiler's barrier
// drain). Everything else (structure, MLP, barrier protocol) unchanged.
// ---------------------------------------------------------------------------

namespace {
constexpr int kT   = 128;
constexpr int kB   = 1024;
constexpr int kLag = 6;
constexpr int kH   = 256;
constexpr int kTc  = 32;          // MLP time chunk
constexpr int kMc  = kTc * kB;    // 32768 rows / chunk
constexpr int kGS  = 66;          // LDS gate row stride (f32)
constexpr int kLdsForce = 98304;  // >80KB => at most 1 block/CU
}

typedef _Float16 half8 __attribute__((ext_vector_type(8)));
typedef _Float16 half2 __attribute__((ext_vector_type(2)));
typedef float f32x4 __attribute__((ext_vector_type(4)));
typedef unsigned long long u64;

__device__ __forceinline__ float sigm(float x) {
    return 1.f / (1.f + exp2f(-1.4426950408889634f * x));
}
__device__ __forceinline__ float tanh_(float x) {
    return 2.f / (1.f + exp2f(-2.8853900817779268f * x)) - 1.f;
}

__device__ __forceinline__ half8 pack(u64 a, u64 b) {
    union { u64 u[2]; half8 h; } r;
    r.u[0] = a; r.u[1] = b;
    return r.h;
}

// ---- inline-asm coherent memory ops (pipelined, unlike __hip_atomic_*) ----
__device__ __forceinline__ void ld_coh(half8& d, const _Float16* p) {
    asm volatile("global_load_dwordx4 %0, %1, off sc0 sc1"
                 : "=v"(d) : "v"(p) : "memory");
}
__device__ __forceinline__ void ld_pln(half8& d, const _Float16* p) {
    asm volatile("global_load_dwordx4 %0, %1, off"
                 : "=v"(d) : "v"(p) : "memory");
}
__device__ __forceinline__ void st_coh(_Float16* p, half2 v) {
    asm volatile("global_store_dword %0, %1, off sc0 sc1"
                 :: "v"(p), "v"(v) : "memory");
}
// wait for all outstanding VMEM; ties the 16 loaded values into the dep chain
// so MFMAs consuming them cannot be scheduled above the wait.
#define WAITCNT_HOLD16(A)                                                     \
    asm volatile("s_waitcnt vmcnt(0)"                                         \
        : "+v"(A[0]), "+v"(A[1]), "+v"(A[2]), "+v"(A[3]),                     \
          "+v"(A[4]), "+v"(A[5]), "+v"(A[6]), "+v"(A[7]),                     \
          "+v"(A[8]), "+v"(A[9]), "+v"(A[10]), "+v"(A[11]),                   \
          "+v"(A[12]), "+v"(A[13]), "+v"(A[14]), "+v"(A[15]))

// ---------------- prep kernels ---------------------------------------------
__global__ __launch_bounds__(256)
void zero_fill(unsigned int* __restrict__ p)
{
    p[blockIdx.x * 256 + threadIdx.x] = 0u;
}

__global__ __launch_bounds__(256)
void cvt_f2h(const float* __restrict__ s, _Float16* __restrict__ d)
{
    const int i = blockIdx.x * 256 + threadIdx.x;
    d[i] = (_Float16)s[i];
}

__global__ __launch_bounds__(256)
void build_wcat(const float* __restrict__ Wih, const float* __restrict__ Whh,
                _Float16* __restrict__ d)
{
    const int i = blockIdx.x * 256 + threadIdx.x;   // over 1024*512
    const int row = i >> 9, col = i & 511;
    const float v = (col < 256) ? Wih[row * 256 + col] : Whh[row * 256 + col - 256];
    d[i] = (_Float16)v;
}

__global__ __launch_bounds__(256)
void add_bias(const float* __restrict__ a, const float* __restrict__ b,
              float* __restrict__ d)
{
    const int i = blockIdx.x * 256 + threadIdx.x;
    d[i] = a[i] + b[i];
}

// ---------------- first layer: u1 = relu(x @ Wi1^T + bi1), K=6, fp16 out ---
__global__ __launch_bounds__(256)
void in_mlp1(const float* __restrict__ x, const float* __restrict__ Wi1,
             const float* __restrict__ bi1, _Float16* __restrict__ out)
{
    const int idx = blockIdx.x * 256 + threadIdx.x;   // over Mc*H
    const int col = idx & (kH - 1);
    const int row = idx >> 8;
    const float* xr = x + (size_t)row * kLag;
    const float* w  = Wi1 + col * kLag;
    float s = bi1[col];
#pragma unroll
    for (int k = 0; k < kLag; ++k) s = fmaf(xr[k], w[k], s);
    out[idx] = (_Float16)fmaxf(s, 0.f);
}

// ---------------- fp16 MFMA GEMM v2 (unchanged, validated) -----------------
__global__ __launch_bounds__(256)
void gemm_h16(const _Float16* __restrict__ A, const _Float16* __restrict__ W,
              const float* __restrict__ bias, _Float16* __restrict__ C)
{
    const int tid = threadIdx.x;
    const int w = tid >> 6, lane = tid & 63, q = lane >> 4, l15 = lane & 15;
    const int n0 = blockIdx.x * 64;
    const int r0 = blockIdx.y * 128 + w * 32;

    half8 bf[4][8];
#pragma unroll
    for (int nt = 0; nt < 4; ++nt)
#pragma unroll
        for (int kk = 0; kk < 8; ++kk)
            bf[nt][kk] = *(const half8*)(W + (size_t)(n0 + nt * 16 + l15) * 256
                                         + kk * 32 + q * 8);
    float bz[4];
#pragma unroll
    for (int nt = 0; nt < 4; ++nt) bz[nt] = bias[n0 + nt * 16 + l15];

#pragma unroll
    for (int rt = 0; rt < 2; ++rt) {
        const _Float16* arow = A + (size_t)(r0 + rt * 16 + l15) * 256 + q * 8;
        half8 af[8];
#pragma unroll
        for (int kk = 0; kk < 8; ++kk) af[kk] = *(const half8*)(arow + kk * 32);
        f32x4 acc[4];
#pragma unroll
        for (int nt = 0; nt < 4; ++nt)
            acc[nt] = (f32x4){bz[nt], bz[nt], bz[nt], bz[nt]};
#pragma unroll
        for (int kk = 0; kk < 8; ++kk)
#pragma unroll
            for (int nt = 0; nt < 4; ++nt)
                acc[nt] = __builtin_amdgcn_mfma_f32_16x16x32_f16(
                    af[kk], bf[nt][kk], acc[nt], 0, 0, 0);
#pragma unroll
        for (int nt = 0; nt < 4; ++nt)
#pragma unroll
            for (int r = 0; r < 4; ++r) {
                const float v = fmaxf(acc[nt][r], 0.f);
                C[(size_t)(r0 + rt * 16 + q * 4 + r) * 256 + n0 + nt * 16 + l15]
                    = (_Float16)v;
            }
    }
}

// ---------------- persistent LSTM helpers ----------------------------------
__device__ __forceinline__ void xbar(unsigned int* __restrict__ cptr,
                                     unsigned int target, int tid)
{
    // per-wave drain: asm sc0sc1 stores are invisible to the compiler's
    // barrier bookkeeping — force all of them to the coherence point first.
    asm volatile("s_waitcnt vmcnt(0)" ::: "memory");
    __syncthreads();
    if (tid == 0) {
        __hip_atomic_fetch_add(cptr, 1u, __ATOMIC_RELAXED,
                               __HIP_MEMORY_SCOPE_AGENT);
        while (__hip_atomic_load(cptr, __ATOMIC_RELAXED,
                                 __HIP_MEMORY_SCOPE_AGENT) < target)
            __builtin_amdgcn_s_sleep(1);
    }
    __syncthreads();
}

// lo-only gather for prologue (plain compiler loads)
__device__ __forceinline__ void gather_lo(const _Float16* lo, int row, int q,
                                          u64* ua)
{
    const u64* plo = (const u64*)(lo + (size_t)row * 256 + q * 8);
#pragma unroll
    for (int kk = 0; kk < 8; ++kk) {
        ua[2*kk]   = plo[kk*8];
        ua[2*kk+1] = plo[kk*8 + 1];
    }
}

__device__ __forceinline__ void gstore(float* __restrict__ gl, int m0, int nb,
                                       int q, int l15,
                                       const f32x4& a0, const f32x4& a1)
{
#pragma unroll
    for (int r = 0; r < 4; ++r) {
        gl[(m0 + q*4 + r) * kGS + nb + l15]      = a0[r];
        gl[(m0 + q*4 + r) * kGS + nb + 16 + l15] = a1[r];
    }
}

// one gate GEMM: A = [lo || hi] (64x512), this wave's 2 col-tiles, 2 row-tiles
// processed sequentially (keeps only 16 loads / 64 VGPRs in flight).
template<bool CLO>
__device__ __forceinline__ void phase_gemm(
    const _Float16* __restrict__ lo, const _Float16* __restrict__ hi,
    const half8 (&B0)[16], const half8 (&B1)[16],
    float* __restrict__ gl, int rtb, int nb, int q, int l15)
{
#pragma unroll
    for (int rt = 0; rt < 2; ++rt) {
        const int row = (rtb + rt) * 16 + l15;
        const _Float16* plo = lo + (size_t)row * 256 + q * 8;
        const _Float16* phi = hi + (size_t)row * 256 + q * 8;
        half8 A[16];
#pragma unroll
        for (int kk = 0; kk < 8; ++kk) {
            if (CLO) ld_coh(A[kk], plo + kk * 32);
            else     ld_pln(A[kk], plo + kk * 32);
            ld_coh(A[8 + kk], phi + kk * 32);
        }
        WAITCNT_HOLD16(A);
        f32x4 a0 = {0.f,0.f,0.f,0.f}, a1 = {0.f,0.f,0.f,0.f};
#pragma unroll
        for (int kk = 0; kk < 16; ++kk) {
            a0 = __builtin_amdgcn_mfma_f32_16x16x32_f16(A[kk], B0[kk], a0, 0,0,0);
            a1 = __builtin_amdgcn_mfma_f32_16x16x32_f16(A[kk], B1[kk], a1, 0,0,0);
        }
        gstore(gl, (rtb + rt) * 16, nb, q, l15, a0, a1);
    }
}

// cell: h stored coherently (sc0 sc1), relu->u stored plain
__device__ __forceinline__ void cell_one(const float* __restrict__ gl,
    int crow, int cc, const float* __restrict__ bs, float* __restrict__ cst,
    _Float16* __restrict__ hout, _Float16* __restrict__ uout)
{
    const float* gr = gl + crow * kGS;
    _Float16 hp[2];
#pragma unroll
    for (int e = 0; e < 2; ++e) {
        const float gi = gr[0*16 + cc + e] + bs[e*4 + 0];
        const float gf = gr[1*16 + cc + e] + bs[e*4 + 1];
        const float gg = gr[2*16 + cc + e] + bs[e*4 + 2];
        const float go = gr[3*16 + cc + e] + bs[e*4 + 3];
        const float c2 = sigm(gf) * cst[e] + sigm(gi) * tanh_(gg);
        cst[e] = c2;
        hp[e] = (_Float16)(sigm(go) * tanh_(c2));
    }
    st_coh(hout + (size_t)crow * 256 + cc, (half2){hp[0], hp[1]});
    if (uout) {
        const _Float16 z = (_Float16)0.f;
        *(half2*)(uout + (size_t)crow * 256 + cc) =
            (half2){hp[0] > z ? hp[0] : z, hp[1] > z ? hp[1] : z};
    }
}

// ---------------- persistent LSTM kernel -----------------------------------
__global__ __launch_bounds__(512, 2)
void lstm_all(_Float16* __restrict__ ubuf,
              const _Float16* __restrict__ Wc0, const _Float16* __restrict__ Wc1,
              const float* __restrict__ bc0, const float* __restrict__ bc1,
              _Float16* __restrict__ h0b, _Float16* __restrict__ h1b,
              unsigned int* __restrict__ cnt)
{
    extern __shared__ char lds[];
    float* gl0 = (float*)lds;             // [64][kGS] layer-0 gates
    float* gl1 = gl0 + 64 * kGS;          // [64][kGS] layer-1 gates

    const int tid = threadIdx.x;
    const int w = tid >> 6, lane = tid & 63, q = lane >> 4, l15 = lane & 15;
    const int wl = w & 3;
    const int rtb = (wl >> 1) * 2;        // row-tile base (0 or 2)
    const int nb  = (wl & 1) * 32;        // gate-col base (0 or 32)
    const int lyr = (w < 4) ? 1 : 0;      // wave's layer

    // ---- XCD discovery -> (bi, js): 96KB LDS => 1 block/CU => 32/XCD ----
    __shared__ int sh_bi, sh_js;
    if (tid == 0) {
        unsigned int xcd = __builtin_amdgcn_s_getreg(20 | (31 << 11)) & 7u;
        unsigned int rank = __hip_atomic_fetch_add(cnt + 512 + xcd * 16, 1u,
            __ATOMIC_RELAXED, __HIP_MEMORY_SCOPE_AGENT);
        sh_bi = (int)(xcd * 2 + (rank >> 4));
        sh_js = (int)(rank & 15);
    }
    __syncthreads();
    const int bi = sh_bi, js = sh_js;
    unsigned int* cptr = cnt + bi * 32;

    // ---- B-fragments of this wave's layer/cols -> 32 half8 in registers ----
    const _Float16* WcL = lyr ? Wc1 : Wc0;
    half8 Bf0[16], Bf1[16];
    {
        const _Float16* wr0 = WcL
            + (size_t)((nb >> 4) * 256 + js * 16 + l15) * 512 + q * 8;
        const _Float16* wr1 = WcL
            + (size_t)(((nb >> 4) + 1) * 256 + js * 16 + l15) * 512 + q * 8;
#pragma unroll
        for (int kk = 0; kk < 16; ++kk) {
            Bf0[kk] = *(const half8*)(wr0 + kk * 32);
            Bf1[kk] = *(const half8*)(wr1 + kk * 32);
        }
    }

    // ---- per-thread biases / states (cell: row tid>>3, cols cc, cc+1) ----
    const int cc = (tid & 7) * 2;
    const int crow = tid >> 3;
    float bs0[8], bs1[8];
#pragma unroll
    for (int e = 0; e < 2; ++e)
#pragma unroll
        for (int g = 0; g < 4; ++g) {
            bs0[e*4 + g] = bc0[g * 256 + js * 16 + cc + e];
            bs1[e*4 + g] = bc1[g * 256 + js * 16 + cc + e];
        }
    float cst0[2] = {0.f, 0.f}, cst1[2] = {0.f, 0.f};
    const size_t rbase = (size_t)bi * 64 * 256;
    const size_t obase = rbase + js * 16;

    // ---- prologue: h0(0) = cell([u(0) | 0] @ W0^T) -> h0b parity 0 ----
    if (lyr == 0) {
#pragma unroll
        for (int rt = 0; rt < 2; ++rt) {
            u64 ua[16];
            gather_lo(ubuf + rbase, (rtb + rt) * 16 + l15, q, ua);
            f32x4 a0 = {0.f,0.f,0.f,0.f}, a1 = {0.f,0.f,0.f,0.f};
#pragma unroll
            for (int kk = 0; kk < 8; ++kk) {
                const half8 af = pack(ua[2*kk], ua[2*kk+1]);
                a0 = __builtin_amdgcn_mfma_f32_16x16x32_f16(af, Bf0[kk], a0, 0,0,0);
                a1 = __builtin_amdgcn_mfma_f32_16x16x32_f16(af, Bf1[kk], a1, 0,0,0);
            }
            gstore(gl0, (rtb + rt) * 16, nb, q, l15, a0, a1);
        }
    }
    __syncthreads();
    cell_one(gl0, crow, cc, bs0, cst0, h0b + obase, nullptr);
    xbar(cptr, 16u, tid);

    // ---- fused phases: t computes h1(t) (waves 0-3) + h0(t+1) (waves 4-7) --
    for (int t = 0; t < kT; ++t) {
        const size_t p  = (size_t)(t & 1) * kB * 256;
        const size_t pn = (size_t)((t & 1) ^ 1) * kB * 256;
        const bool hasB = (t < kT - 1);
        if (lyr == 1) {
            // layer-1 A = [h0(t) | h1(t-1)]
            phase_gemm<true>(h0b + p + rbase, h1b + pn + rbase,
                             Bf0, Bf1, gl1, rtb, nb, q, l15);
        } else if (hasB) {
            // layer-0 A = [u(t+1) | h0(t)]
            phase_gemm<false>(ubuf + (size_t)(t + 1) * kB * 256 + rbase,
                              h0b + p + rbase,
                              Bf0, Bf1, gl0, rtb, nb, q, l15);
        }
        __syncthreads();
        cell_one(gl1, crow, cc, bs1, cst1, h1b + p + obase,
                 ubuf + (size_t)t * kB * 256 + obase);
        if (hasB) {
            cell_one(gl0, crow, cc, bs0, cst0, h0b + pn + obase, nullptr);
            xbar(cptr, (unsigned)(16 * (t + 2)), tid);
        }
    }
}

// ---------------- last layer: y = y2 @ Wo3^T + bo3, N=6, fp16 in -----------
__global__ __launch_bounds__(256)
void out_mlp3(const _Float16* __restrict__ y2, const float* __restrict__ Wo3,
              const float* __restrict__ bo3, float* __restrict__ out)
{
    const int lane = threadIdx.x & 63;
    const int row  = blockIdx.x * 4 + (threadIdx.x >> 6);
    const _Float16* yr = y2 + (size_t)row * kH + lane * 4;
    const float a0 = (float)yr[0], a1 = (float)yr[1], a2 = (float)yr[2], a3 = (float)yr[3];
    float s[kLag];
#pragma unroll
    for (int o = 0; o < kLag; ++o) {
        const float4 wv = *(const float4*)(Wo3 + o * kH + lane * 4);
        s[o] = a0 * wv.x + a1 * wv.y + a2 * wv.z + a3 * wv.w;
    }
#pragma unroll
    for (int off = 32; off > 0; off >>= 1) {
#pragma unroll
        for (int o = 0; o < kLag; ++o) s[o] += __shfl_down(s[o], off);
    }
    if (lane == 0) {
#pragma unroll
        for (int o = 0; o < kLag; ++o)
            out[(size_t)row * kLag + o] = s[o] + bo3[o];
    }
}

// ---------------------------------------------------------------------------
extern "C" void kernel_launch(void* const* d_in, const int* in_sizes, int n_in,
                              void* d_out, int out_size, void* d_ws, size_t ws_size,
                              hipStream_t stream)
{
    const float* x    = (const float*)d_in[0];
    const float* Wi1  = (const float*)d_in[1];
    const float* bi1  = (const float*)d_in[2];
    const float* Wi2  = (const float*)d_in[3];
    const float* bi2  = (const float*)d_in[4];
    const float* Wi3  = (const float*)d_in[5];
    const float* bi3  = (const float*)d_in[6];
    const float* Wih0 = (const float*)d_in[7];
    const float* Whh0 = (const float*)d_in[8];
    const float* bih0 = (const float*)d_in[9];
    const float* bhh0 = (const float*)d_in[10];
    const float* Wih1 = (const float*)d_in[11];
    const float* Whh1 = (const float*)d_in[12];
    const float* bih1 = (const float*)d_in[13];
    const float* bhh1 = (const float*)d_in[14];
    const float* Wo1  = (const float*)d_in[15];
    const float* bo1  = (const float*)d_in[16];
    const float* Wo2  = (const float*)d_in[17];
    const float* bo2  = (const float*)d_in[18];
    const float* Wo3  = (const float*)d_in[19];
    const float* bo3  = (const float*)d_in[20];
    float* outp = (float*)d_out;

    // ---- workspace layout (~106 MB) ----
    char* p = (char*)d_ws;
    _Float16* ubuf = (_Float16*)p;  p += (size_t)kT * kB * kH * 2;   // 67.1 MB
    _Float16* s1   = (_Float16*)p;  p += (size_t)kMc * kH * 2;       // 16.8 MB
    _Float16* s2   = (_Float16*)p;  p += (size_t)kMc * kH * 2;       // 16.8 MB
    _Float16* Wc0  = (_Float16*)p;  p += (size_t)1024 * 512 * 2;     // 1 MB
    _Float16* Wc1  = (_Float16*)p;  p += (size_t)1024 * 512 * 2;     // 1 MB
    _Float16* W2h  = (_Float16*)p;  p += (size_t)kH * kH * 2;
    _Float16* W3h  = (_Float16*)p;  p += (size_t)kH * kH * 2;
    _Float16* Wo1h = (_Float16*)p;  p += (size_t)kH * kH * 2;
    _Float16* Wo2h = (_Float16*)p;  p += (size_t)kH * kH * 2;
    float* bc0 = (float*)p;  p += 1024 * 4;
    float* bc1 = (float*)p;  p += 1024 * 4;
    // zeroed region: h double-buffers + counters (contiguous)
    _Float16* h0b = (_Float16*)p;  p += (size_t)2 * kB * kH * 2;     // 1 MB
    _Float16* h1b = (_Float16*)p;  p += (size_t)2 * kB * kH * 2;     // 1 MB
    unsigned int* cnt = (unsigned int*)p;  p += 4096;  // 16 group + 8 xcd ctrs

    // ---- prep ----
    zero_fill<<<2052, 256, 0, stream>>>((unsigned int*)h0b);
    cvt_f2h<<<kH * kH / 256, 256, 0, stream>>>(Wi2, W2h);
    cvt_f2h<<<kH * kH / 256, 256, 0, stream>>>(Wi3, W3h);
    cvt_f2h<<<kH * kH / 256, 256, 0, stream>>>(Wo1, Wo1h);
    cvt_f2h<<<kH * kH / 256, 256, 0, stream>>>(Wo2, Wo2h);
    build_wcat<<<1024 * 512 / 256, 256, 0, stream>>>(Wih0, Whh0, Wc0);
    build_wcat<<<1024 * 512 / 256, 256, 0, stream>>>(Wih1, Whh1, Wc1);
    add_bias<<<4, 256, 0, stream>>>(bih0, bhh0, bc0);
    add_bias<<<4, 256, 0, stream>>>(bih1, bhh1, bc1);

    // ---- input MLP (chunked): x -> s1 -> s2 -> ubuf ----
    for (int c = 0; c < kT / kTc; ++c) {
        in_mlp1<<<kMc * kH / 256, 256, 0, stream>>>(
            x + (size_t)c * kMc * kLag, Wi1, bi1, s1);
        gemm_h16<<<dim3(4, kMc / 128), 256, 0, stream>>>(s1, W2h, bi2, s2);
        gemm_h16<<<dim3(4, kMc / 128), 256, 0, stream>>>(
            s2, W3h, bi3, ubuf + (size_t)c * kMc * kH);
    }

    // ---- LSTM: cooperative, weights in VGPRs, XCD-local barriers ----
    static bool attr_set = false;
    if (!attr_set) {
        hipFuncSetAttribute((const void*)lstm_all,
                            hipFuncAttributeMaxDynamicSharedMemorySize, kLdsForce);
        attr_set = true;
    }
    void* args[] = {&ubuf, &Wc0, &Wc1, &bc0, &bc1, &h0b, &h1b, &cnt};
    hipLaunchCooperativeKernel((const void*)lstm_all, dim3(256), dim3(512),
                               args, kLdsForce, stream);

    // ---- output MLP (chunked): ubuf -> s1 -> s2 -> out ----
    for (int c = 0; c < kT / kTc; ++c) {
        gemm_h16<<<dim3(4, kMc / 128), 256, 0, stream>>>(
            ubuf + (size_t)c * kMc * kH, Wo1h, bo1, s1);
        gemm_h16<<<dim3(4, kMc / 128), 256, 0, stream>>>(s1, Wo2h, bo2, s2);
        out_mlp3<<<kMc / 4, 256, 0, stream>>>(
            s2, Wo3, bo3, outp + (size_t)c * kMc * kLag);
    }
}

// Round 10
// 1957.540 us; speedup vs baseline: 1.7209x; 1.0553x over previous
//
#include <hip/hip_runtime.h>
#include <math.h>

// ---------------------------------------------------------------------------
// RNN_63153199120819 — Round 10: L2 data path + LLC barrier (hang fix).
// R9 hung: plain global atomics execute at the DEVICE coherence point (LLC,
// why atomicAdd is device-scope by default), but the sc0-only poll read the
// local L2's stale clean copy of the counter line -> infinite spin. Fix:
// barrier = round-8's proven agent-scope atomic inc + agent-scope atomic
// load poll (both LLC). Data path keeps R9's design: h stores PLAIN (write-
// back into the producer/consumer-shared XCD L2), h loads `sc0` only (bypass
// stale L1, hit that same L2, ~200cy). Store->barrier ordering: vmcnt drain
// before the LLC increment.
// ---------------------------------------------------------------------------

namespace {
constexpr int kT   = 128;
constexpr int kB   = 1024;
constexpr int kLag = 6;
constexpr int kH   = 256;
constexpr int kTc  = 32;          // MLP time chunk
constexpr int kMc  = kTc * kB;    // 32768 rows / chunk
constexpr int kGS  = 67;          // LDS gate row stride (f32), odd => banks spread
constexpr int kLdsForce = 98304;  // >80KB => at most 1 block/CU
}

typedef _Float16 half8 __attribute__((ext_vector_type(8)));
typedef _Float16 half2 __attribute__((ext_vector_type(2)));
typedef float f32x4 __attribute__((ext_vector_type(4)));
typedef unsigned long long u64;

__device__ __forceinline__ float sigm(float x) {
    return 1.f / (1.f + exp2f(-1.4426950408889634f * x));
}
__device__ __forceinline__ float tanh_(float x) {
    return 2.f / (1.f + exp2f(-2.8853900817779268f * x)) - 1.f;
}

__device__ __forceinline__ half8 pack(u64 a, u64 b) {
    union { u64 u[2]; half8 h; } r;
    r.u[0] = a; r.u[1] = b;
    return r.h;
}

// ---- inline-asm memory ops ------------------------------------------------
// L1-bypass load served by the XCD's shared L2 (no sc1 -> no LLC trip)
__device__ __forceinline__ void ld_l2(half8& d, const _Float16* p) {
    asm volatile("global_load_dwordx4 %0, %1, off sc0"
                 : "=v"(d) : "v"(p) : "memory");
}
__device__ __forceinline__ void ld_pln(half8& d, const _Float16* p) {
    asm volatile("global_load_dwordx4 %0, %1, off"
                 : "=v"(d) : "v"(p) : "memory");
}
// wait for all outstanding VMEM; ties the 16 loaded values into the dep chain
#define WAITCNT_HOLD16(A)                                                     \
    asm volatile("s_waitcnt vmcnt(0)"                                         \
        : "+v"(A[0]), "+v"(A[1]), "+v"(A[2]), "+v"(A[3]),                     \
          "+v"(A[4]), "+v"(A[5]), "+v"(A[6]), "+v"(A[7]),                     \
          "+v"(A[8]), "+v"(A[9]), "+v"(A[10]), "+v"(A[11]),                   \
          "+v"(A[12]), "+v"(A[13]), "+v"(A[14]), "+v"(A[15]))

// ---------------- prep kernels ---------------------------------------------
__global__ __launch_bounds__(256)
void zero_fill(unsigned int* __restrict__ p)
{
    p[blockIdx.x * 256 + threadIdx.x] = 0u;
}

__global__ __launch_bounds__(256)
void cvt_f2h(const float* __restrict__ s, _Float16* __restrict__ d)
{
    const int i = blockIdx.x * 256 + threadIdx.x;
    d[i] = (_Float16)s[i];
}

__global__ __launch_bounds__(256)
void build_wcat(const float* __restrict__ Wih, const float* __restrict__ Whh,
                _Float16* __restrict__ d)
{
    const int i = blockIdx.x * 256 + threadIdx.x;   // over 1024*512
    const int row = i >> 9, col = i & 511;
    const float v = (col < 256) ? Wih[row * 256 + col] : Whh[row * 256 + col - 256];
    d[i] = (_Float16)v;
}

__global__ __launch_bounds__(256)
void add_bias(const float* __restrict__ a, const float* __restrict__ b,
              float* __restrict__ d)
{
    const int i = blockIdx.x * 256 + threadIdx.x;
    d[i] = a[i] + b[i];
}

// ---------------- first layer: u1 = relu(x @ Wi1^T + bi1), K=6, fp16 out ---
__global__ __launch_bounds__(256)
void in_mlp1(const float* __restrict__ x, const float* __restrict__ Wi1,
             const float* __restrict__ bi1, _Float16* __restrict__ out)
{
    const int idx = blockIdx.x * 256 + threadIdx.x;   // over Mc*H
    const int col = idx & (kH - 1);
    const int row = idx >> 8;
    const float* xr = x + (size_t)row * kLag;
    const float* w  = Wi1 + col * kLag;
    float s = bi1[col];
#pragma unroll
    for (int k = 0; k < kLag; ++k) s = fmaf(xr[k], w[k], s);
    out[idx] = (_Float16)fmaxf(s, 0.f);
}

// ---------------- fp16 MFMA GEMM v2 (unchanged, validated) -----------------
__global__ __launch_bounds__(256)
void gemm_h16(const _Float16* __restrict__ A, const _Float16* __restrict__ W,
              const float* __restrict__ bias, _Float16* __restrict__ C)
{
    const int tid = threadIdx.x;
    const int w = tid >> 6, lane = tid & 63, q = lane >> 4, l15 = lane & 15;
    const int n0 = blockIdx.x * 64;
    const int r0 = blockIdx.y * 128 + w * 32;

    half8 bf[4][8];
#pragma unroll
    for (int nt = 0; nt < 4; ++nt)
#pragma unroll
        for (int kk = 0; kk < 8; ++kk)
            bf[nt][kk] = *(const half8*)(W + (size_t)(n0 + nt * 16 + l15) * 256
                                         + kk * 32 + q * 8);
    float bz[4];
#pragma unroll
    for (int nt = 0; nt < 4; ++nt) bz[nt] = bias[n0 + nt * 16 + l15];

#pragma unroll
    for (int rt = 0; rt < 2; ++rt) {
        const _Float16* arow = A + (size_t)(r0 + rt * 16 + l15) * 256 + q * 8;
        half8 af[8];
#pragma unroll
        for (int kk = 0; kk < 8; ++kk) af[kk] = *(const half8*)(arow + kk * 32);
        f32x4 acc[4];
#pragma unroll
        for (int nt = 0; nt < 4; ++nt)
            acc[nt] = (f32x4){bz[nt], bz[nt], bz[nt], bz[nt]};
#pragma unroll
        for (int kk = 0; kk < 8; ++kk)
#pragma unroll
            for (int nt = 0; nt < 4; ++nt)
                acc[nt] = __builtin_amdgcn_mfma_f32_16x16x32_f16(
                    af[kk], bf[nt][kk], acc[nt], 0, 0, 0);
#pragma unroll
        for (int nt = 0; nt < 4; ++nt)
#pragma unroll
            for (int r = 0; r < 4; ++r) {
                const float v = fmaxf(acc[nt][r], 0.f);
                C[(size_t)(r0 + rt * 16 + q * 4 + r) * 256 + n0 + nt * 16 + l15]
                    = (_Float16)v;
            }
    }
}

// ---------------- persistent LSTM helpers ----------------------------------
// barrier: drain stores to L2, then LLC-scope atomic inc + LLC atomic poll
// (round-8 protocol — atomics and poll agree on the coherence point).
__device__ __forceinline__ void xbar(unsigned int* __restrict__ cptr,
                                     unsigned int target, int tid)
{
    asm volatile("s_waitcnt vmcnt(0)" ::: "memory");
    __syncthreads();
    if (tid == 0) {
        __hip_atomic_fetch_add(cptr, 1u, __ATOMIC_RELAXED,
                               __HIP_MEMORY_SCOPE_AGENT);
        while (__hip_atomic_load(cptr, __ATOMIC_RELAXED,
                                 __HIP_MEMORY_SCOPE_AGENT) < target)
            __builtin_amdgcn_s_sleep(1);
    }
    __syncthreads();
}

// lo-only gather for prologue (plain compiler loads)
__device__ __forceinline__ void gather_lo(const _Float16* lo, int row, int q,
                                          u64* ua)
{
    const u64* plo = (const u64*)(lo + (size_t)row * 256 + q * 8);
#pragma unroll
    for (int kk = 0; kk < 8; ++kk) {
        ua[2*kk]   = plo[kk*8];
        ua[2*kk+1] = plo[kk*8 + 1];
    }
}

__device__ __forceinline__ void gstore(float* __restrict__ gl, int m0, int nb,
                                       int q, int l15,
                                       const f32x4& a0, const f32x4& a1)
{
#pragma unroll
    for (int r = 0; r < 4; ++r) {
        gl[(m0 + q*4 + r) * kGS + nb + l15]      = a0[r];
        gl[(m0 + q*4 + r) * kGS + nb + 16 + l15] = a1[r];
    }
}

// one gate GEMM: A = [lo || hi] (64x512), this wave's 2 col-tiles, 2 row-tiles
template<bool CLO>
__device__ __forceinline__ void phase_gemm(
    const _Float16* __restrict__ lo, const _Float16* __restrict__ hi,
    const half8 (&B0)[16], const half8 (&B1)[16],
    float* __restrict__ gl, int rtb, int nb, int q, int l15)
{
#pragma unroll
    for (int rt = 0; rt < 2; ++rt) {
        const int row = (rtb + rt) * 16 + l15;
        const _Float16* plo = lo + (size_t)row * 256 + q * 8;
        const _Float16* phi = hi + (size_t)row * 256 + q * 8;
        half8 A[16];
#pragma unroll
        for (int kk = 0; kk < 8; ++kk) {
            if (CLO) ld_l2(A[kk], plo + kk * 32);
            else     ld_pln(A[kk], plo + kk * 32);
            ld_l2(A[8 + kk], phi + kk * 32);
        }
        WAITCNT_HOLD16(A);
        f32x4 a0 = {0.f,0.f,0.f,0.f}, a1 = {0.f,0.f,0.f,0.f};
#pragma unroll
        for (int kk = 0; kk < 16; ++kk) {
            a0 = __builtin_amdgcn_mfma_f32_16x16x32_f16(A[kk], B0[kk], a0, 0,0,0);
            a1 = __builtin_amdgcn_mfma_f32_16x16x32_f16(A[kk], B1[kk], a1, 0,0,0);
        }
        gstore(gl, (rtb + rt) * 16, nb, q, l15, a0, a1);
    }
}

// cell: h + relu->u stored with PLAIN stores (land in the shared XCD L2)
__device__ __forceinline__ void cell_one(const float* __restrict__ gl,
    int crow, int cc, const float* __restrict__ bs, float* __restrict__ cst,
    _Float16* __restrict__ hout, _Float16* __restrict__ uout)
{
    const float* gr = gl + crow * kGS;
    _Float16 hp[2];
#pragma unroll
    for (int e = 0; e < 2; ++e) {
        const float gi = gr[0*16 + cc + e] + bs[e*4 + 0];
        const float gf = gr[1*16 + cc + e] + bs[e*4 + 1];
        const float gg = gr[2*16 + cc + e] + bs[e*4 + 2];
        const float go = gr[3*16 + cc + e] + bs[e*4 + 3];
        const float c2 = sigm(gf) * cst[e] + sigm(gi) * tanh_(gg);
        cst[e] = c2;
        hp[e] = (_Float16)(sigm(go) * tanh_(c2));
    }
    *(half2*)(hout + (size_t)crow * 256 + cc) = (half2){hp[0], hp[1]};
    if (uout) {
        const _Float16 z = (_Float16)0.f;
        *(half2*)(uout + (size_t)crow * 256 + cc) =
            (half2){hp[0] > z ? hp[0] : z, hp[1] > z ? hp[1] : z};
    }
}

// ---------------- persistent LSTM kernel -----------------------------------
__global__ __launch_bounds__(512, 2)
void lstm_all(_Float16* __restrict__ ubuf,
              const _Float16* __restrict__ Wc0, const _Float16* __restrict__ Wc1,
              const float* __restrict__ bc0, const float* __restrict__ bc1,
              _Float16* __restrict__ h0b, _Float16* __restrict__ h1b,
              unsigned int* __restrict__ cnt)
{
    extern __shared__ char lds[];
    float* gl0 = (float*)lds;             // [64][kGS] layer-0 gates
    float* gl1 = gl0 + 64 * kGS;          // [64][kGS] layer-1 gates

    const int tid = threadIdx.x;
    const int w = tid >> 6, lane = tid & 63, q = lane >> 4, l15 = lane & 15;
    const int wl = w & 3;
    const int rtb = (wl >> 1) * 2;        // row-tile base (0 or 2)
    const int nb  = (wl & 1) * 32;        // gate-col base (0 or 32)
    const int lyr = (w < 4) ? 1 : 0;      // wave's layer

    // ---- XCD discovery -> (bi, js): 96KB LDS => 1 block/CU => 32/XCD ----
    __shared__ int sh_bi, sh_js;
    if (tid == 0) {
        unsigned int xcd = __builtin_amdgcn_s_getreg(20 | (31 << 11)) & 7u;
        unsigned int rank = __hip_atomic_fetch_add(cnt + 512 + xcd * 16, 1u,
            __ATOMIC_RELAXED, __HIP_MEMORY_SCOPE_AGENT);
        sh_bi = (int)(xcd * 2 + (rank >> 4));
        sh_js = (int)(rank & 15);
    }
    __syncthreads();
    const int bi = sh_bi, js = sh_js;
    unsigned int* cptr = cnt + bi * 32;   // group counter (LLC line)

    // ---- B-fragments of this wave's layer/cols -> 32 half8 in registers ----
    const _Float16* WcL = lyr ? Wc1 : Wc0;
    half8 Bf0[16], Bf1[16];
    {
        const _Float16* wr0 = WcL
            + (size_t)((nb >> 4) * 256 + js * 16 + l15) * 512 + q * 8;
        const _Float16* wr1 = WcL
            + (size_t)(((nb >> 4) + 1) * 256 + js * 16 + l15) * 512 + q * 8;
#pragma unroll
        for (int kk = 0; kk < 16; ++kk) {
            Bf0[kk] = *(const half8*)(wr0 + kk * 32);
            Bf1[kk] = *(const half8*)(wr1 + kk * 32);
        }
    }

    // ---- per-thread biases / states (cell: row tid>>3, cols cc, cc+1) ----
    const int cc = (tid & 7) * 2;
    const int crow = tid >> 3;
    float bs0[8], bs1[8];
#pragma unroll
    for (int e = 0; e < 2; ++e)
#pragma unroll
        for (int g = 0; g < 4; ++g) {
            bs0[e*4 + g] = bc0[g * 256 + js * 16 + cc + e];
            bs1[e*4 + g] = bc1[g * 256 + js * 16 + cc + e];
        }
    float cst0[2] = {0.f, 0.f}, cst1[2] = {0.f, 0.f};
    const size_t rbase = (size_t)bi * 64 * 256;
    const size_t obase = rbase + js * 16;

    // ---- prologue: h0(0) = cell([u(0) | 0] @ W0^T) -> h0b parity 0 ----
    if (lyr == 0) {
#pragma unroll
        for (int rt = 0; rt < 2; ++rt) {
            u64 ua[16];
            gather_lo(ubuf + rbase, (rtb + rt) * 16 + l15, q, ua);
            f32x4 a0 = {0.f,0.f,0.f,0.f}, a1 = {0.f,0.f,0.f,0.f};
#pragma unroll
            for (int kk = 0; kk < 8; ++kk) {
                const half8 af = pack(ua[2*kk], ua[2*kk+1]);
                a0 = __builtin_amdgcn_mfma_f32_16x16x32_f16(af, Bf0[kk], a0, 0,0,0);
                a1 = __builtin_amdgcn_mfma_f32_16x16x32_f16(af, Bf1[kk], a1, 0,0,0);
            }
            gstore(gl0, (rtb + rt) * 16, nb, q, l15, a0, a1);
        }
    }
    __syncthreads();
    cell_one(gl0, crow, cc, bs0, cst0, h0b + obase, nullptr);
    xbar(cptr, 16u, tid);

    // ---- fused phases: t computes h1(t) (waves 0-3) + h0(t+1) (waves 4-7) --
    for (int t = 0; t < kT; ++t) {
        const size_t p  = (size_t)(t & 1) * kB * 256;
        const size_t pn = (size_t)((t & 1) ^ 1) * kB * 256;
        const bool hasB = (t < kT - 1);
        if (lyr == 1) {
            // layer-1 A = [h0(t) | h1(t-1)]
            phase_gemm<true>(h0b + p + rbase, h1b + pn + rbase,
                             Bf0, Bf1, gl1, rtb, nb, q, l15);
        } else if (hasB) {
            // layer-0 A = [u(t+1) | h0(t)]
            phase_gemm<false>(ubuf + (size_t)(t + 1) * kB * 256 + rbase,
                              h0b + p + rbase,
                              Bf0, Bf1, gl0, rtb, nb, q, l15);
        }
        __syncthreads();
        cell_one(gl1, crow, cc, bs1, cst1, h1b + p + obase,
                 ubuf + (size_t)t * kB * 256 + obase);
        if (hasB) {
            cell_one(gl0, crow, cc, bs0, cst0, h0b + pn + obase, nullptr);
            xbar(cptr, (unsigned)(16 * (t + 2)), tid);
        }
    }
}

// ---------------- last layer: y = y2 @ Wo3^T + bo3, N=6, fp16 in -----------
__global__ __launch_bounds__(256)
void out_mlp3(const _Float16* __restrict__ y2, const float* __restrict__ Wo3,
              const float* __restrict__ bo3, float* __restrict__ out)
{
    const int lane = threadIdx.x & 63;
    const int row  = blockIdx.x * 4 + (threadIdx.x >> 6);
    const _Float16* yr = y2 + (size_t)row * kH + lane * 4;
    const float a0 = (float)yr[0], a1 = (float)yr[1], a2 = (float)yr[2], a3 = (float)yr[3];
    float s[kLag];
#pragma unroll
    for (int o = 0; o < kLag; ++o) {
        const float4 wv = *(const float4*)(Wo3 + o * kH + lane * 4);
        s[o] = a0 * wv.x + a1 * wv.y + a2 * wv.z + a3 * wv.w;
    }
#pragma unroll
    for (int off = 32; off > 0; off >>= 1) {
#pragma unroll
        for (int o = 0; o < kLag; ++o) s[o] += __shfl_down(s[o], off);
    }
    if (lane == 0) {
#pragma unroll
        for (int o = 0; o < kLag; ++o)
            out[(size_t)row * kLag + o] = s[o] + bo3[o];
    }
}

// ---------------------------------------------------------------------------
extern "C" void kernel_launch(void* const* d_in, const int* in_sizes, int n_in,
                              void* d_out, int out_size, void* d_ws, size_t ws_size,
                              hipStream_t stream)
{
    const float* x    = (const float*)d_in[0];
    const float* Wi1  = (const float*)d_in[1];
    const float* bi1  = (const float*)d_in[2];
    const float* Wi2  = (const float*)d_in[3];
    const float* bi2  = (const float*)d_in[4];
    const float* Wi3  = (const float*)d_in[5];
    const float* bi3  = (const float*)d_in[6];
    const float* Wih0 = (const float*)d_in[7];
    const float* Whh0 = (const float*)d_in[8];
    const float* bih0 = (const float*)d_in[9];
    const float* bhh0 = (const float*)d_in[10];
    const float* Wih1 = (const float*)d_in[11];
    const float* Whh1 = (const float*)d_in[12];
    const float* bih1 = (const float*)d_in[13];
    const float* bhh1 = (const float*)d_in[14];
    const float* Wo1  = (const float*)d_in[15];
    const float* bo1  = (const float*)d_in[16];
    const float* Wo2  = (const float*)d_in[17];
    const float* bo2  = (const float*)d_in[18];
    const float* Wo3  = (const float*)d_in[19];
    const float* bo3  = (const float*)d_in[20];
    float* outp = (float*)d_out;

    // ---- workspace layout (~106 MB) ----
    char* p = (char*)d_ws;
    _Float16* ubuf = (_Float16*)p;  p += (size_t)kT * kB * kH * 2;   // 67.1 MB
    _Float16* s1   = (_Float16*)p;  p += (size_t)kMc * kH * 2;       // 16.8 MB
    _Float16* s2   = (_Float16*)p;  p += (size_t)kMc * kH * 2;       // 16.8 MB
    _Float16* Wc0  = (_Float16*)p;  p += (size_t)1024 * 512 * 2;     // 1 MB
    _Float16* Wc1  = (_Float16*)p;  p += (size_t)1024 * 512 * 2;     // 1 MB
    _Float16* W2h  = (_Float16*)p;  p += (size_t)kH * kH * 2;
    _Float16* W3h  = (_Float16*)p;  p += (size_t)kH * kH * 2;
    _Float16* Wo1h = (_Float16*)p;  p += (size_t)kH * kH * 2;
    _Float16* Wo2h = (_Float16*)p;  p += (size_t)kH * kH * 2;
    float* bc0 = (float*)p;  p += 1024 * 4;
    float* bc1 = (float*)p;  p += 1024 * 4;
    // zeroed region: h double-buffers + counters (contiguous)
    _Float16* h0b = (_Float16*)p;  p += (size_t)2 * kB * kH * 2;     // 1 MB
    _Float16* h1b = (_Float16*)p;  p += (size_t)2 * kB * kH * 2;     // 1 MB
    unsigned int* cnt = (unsigned int*)p;  p += 4096;  // 16 group + 8 xcd ctrs

    // ---- prep ----
    zero_fill<<<2052, 256, 0, stream>>>((unsigned int*)h0b);
    cvt_f2h<<<kH * kH / 256, 256, 0, stream>>>(Wi2, W2h);
    cvt_f2h<<<kH * kH / 256, 256, 0, stream>>>(Wi3, W3h);
    cvt_f2h<<<kH * kH / 256, 256, 0, stream>>>(Wo1, Wo1h);
    cvt_f2h<<<kH * kH / 256, 256, 0, stream>>>(Wo2, Wo2h);
    build_wcat<<<1024 * 512 / 256, 256, 0, stream>>>(Wih0, Whh0, Wc0);
    build_wcat<<<1024 * 512 / 256, 256, 0, stream>>>(Wih1, Whh1, Wc1);
    add_bias<<<4, 256, 0, stream>>>(bih0, bhh0, bc0);
    add_bias<<<4, 256, 0, stream>>>(bih1, bhh1, bc1);

    // ---- input MLP (chunked): x -> s1 -> s2 -> ubuf ----
    for (int c = 0; c < kT / kTc; ++c) {
        in_mlp1<<<kMc * kH / 256, 256, 0, stream>>>(
            x + (size_t)c * kMc * kLag, Wi1, bi1, s1);
        gemm_h16<<<dim3(4, kMc / 128), 256, 0, stream>>>(s1, W2h, bi2, s2);
        gemm_h16<<<dim3(4, kMc / 128), 256, 0, stream>>>(
            s2, W3h, bi3, ubuf + (size_t)c * kMc * kH);
    }

    // ---- LSTM: cooperative, weights in VGPRs, L2 data / LLC barrier ----
    static bool attr_set = false;
    if (!attr_set) {
        hipFuncSetAttribute((const void*)lstm_all,
                            hipFuncAttributeMaxDynamicSharedMemorySize, kLdsForce);
        attr_set = true;
    }
    void* args[] = {&ubuf, &Wc0, &Wc1, &bc0, &bc1, &h0b, &h1b, &cnt};
    hipLaunchCooperativeKernel((const void*)lstm_all, dim3(256), dim3(512),
                               args, kLdsForce, stream);

    // ---- output MLP (chunked): ubuf -> s1 -> s2 -> out ----
    for (int c = 0; c < kT / kTc; ++c) {
        gemm_h16<<<dim3(4, kMc / 128), 256, 0, stream>>>(
            ubuf + (size_t)c * kMc * kH, Wo1h, bo1, s1);
        gemm_h16<<<dim3(4, kMc / 128), 256, 0, stream>>>(s1, Wo2h, bo2, s2);
        out_mlp3<<<kMc / 4, 256, 0, stream>>>(
            s2, Wo3, bo3, outp + (size_t)c * kMc * kLag);
    }
}